// Round 1
// baseline (565.178 us; speedup 1.0000x reference)
//
#include <hip/hip_runtime.h>

#define Bv 8
#define Cv 64
#define Lv 65536
#define TPB 256
#define BLKS_PER_B (Lv / TPB)        // 256
#define GRID1 (Bv * BLKS_PER_B)      // 2048

// ---------------------------------------------------------------------------
// Pass 1: fused gate + fuse conv + residual + ReLU, writes pre-GN output and
// per-block (sum, sumsq) partials for GroupNorm statistics.
// One thread = one spatial location l (all 64 channels in registers).
// ---------------------------------------------------------------------------
__global__ __launch_bounds__(TPB, 3)
void pass1(const float* __restrict__ x, const float* __restrict__ inj0,
           const float* __restrict__ inj1, const float* __restrict__ resid,
           const float* __restrict__ gate_w, const float* __restrict__ gate_b,
           const float* __restrict__ fuse_w, const float* __restrict__ fuse_b,
           float* __restrict__ out, float* __restrict__ partials)
{
    __shared__ float gw[Cv * Cv];   // gate_w row-major [o][c]
    __shared__ float fwT[Cv * Cv];  // fuse_w transposed [o][o2] = fuse_w[o2][o]
    __shared__ float gb2[Cv], fb[Cv];
    __shared__ float r1[TPB], r2[TPB];

    const int tid = threadIdx.x;
    for (int i = tid; i < Cv * Cv; i += TPB) {
        gw[i]  = gate_w[i];
        fwT[i] = fuse_w[((i & 63) << 6) | (i >> 6)];
    }
    if (tid < Cv) { gb2[tid] = 2.0f * gate_b[tid]; fb[tid] = fuse_b[tid]; }
    __syncthreads();

    const int b    = blockIdx.x / BLKS_PER_B;
    const int lb   = blockIdx.x % BLKS_PER_B;
    const int base = b * (Cv * Lv) + lb * TPB + tid;

    float s[Cv];   // inj0 + inj1 + 2x  (gate matvec input)
    float t[Cv];   // fuse matvec accumulator

    #pragma unroll
    for (int c = 0; c < Cv; ++c) {
        const int idx = base + c * Lv;
        s[c] = inj0[idx] + inj1[idx] + 2.0f * x[idx];
        t[c] = 0.0f;
    }

    // Fused streaming over intermediate channel o:
    //   g    = gate_w[o,:] . s + 2*gate_b[o]
    //   acc  = x[o] * g
    //   t[:] += fuse_w[:,o] * acc
    #pragma unroll 2
    for (int o = 0; o < Cv; ++o) {
        float g = gb2[o];
        const float4* gr = reinterpret_cast<const float4*>(&gw[o << 6]);
        #pragma unroll
        for (int q = 0; q < 16; ++q) {
            const float4 w = gr[q];
            g = fmaf(w.x, s[4 * q + 0], g);
            g = fmaf(w.y, s[4 * q + 1], g);
            g = fmaf(w.z, s[4 * q + 2], g);
            g = fmaf(w.w, s[4 * q + 3], g);
        }
        const float acc = x[base + o * Lv] * g;   // x re-read: L1/L2 hit
        const float4* fr = reinterpret_cast<const float4*>(&fwT[o << 6]);
        #pragma unroll
        for (int q = 0; q < 16; ++q) {
            const float4 w = fr[q];
            t[4 * q + 0] = fmaf(w.x, acc, t[4 * q + 0]);
            t[4 * q + 1] = fmaf(w.y, acc, t[4 * q + 1]);
            t[4 * q + 2] = fmaf(w.z, acc, t[4 * q + 2]);
            t[4 * q + 3] = fmaf(w.w, acc, t[4 * q + 3]);
        }
    }

    // Epilogue: bias + residual + ReLU, store pre-GN output, local stats.
    float lsum = 0.0f, lsq = 0.0f;
    #pragma unroll
    for (int o = 0; o < Cv; ++o) {
        float v = t[o] + fb[o] + resid[base + o * Lv];
        v = fmaxf(v, 0.0f);
        out[base + o * Lv] = v;
        lsum += v;
        lsq = fmaf(v, v, lsq);
    }

    // Deterministic block reduction -> per-block partials.
    r1[tid] = lsum; r2[tid] = lsq;
    __syncthreads();
    #pragma unroll
    for (int st = TPB / 2; st > 0; st >>= 1) {
        if (tid < st) { r1[tid] += r1[tid + st]; r2[tid] += r2[tid + st]; }
        __syncthreads();
    }
    if (tid == 0) {
        partials[2 * blockIdx.x]     = r1[0];
        partials[2 * blockIdx.x + 1] = r2[0];
    }
}

// ---------------------------------------------------------------------------
// Pass 2: reduce 256 partials per batch -> per-(b,c) scale/bias.
// ---------------------------------------------------------------------------
__global__ __launch_bounds__(256)
void pass2(const float* __restrict__ partials, const float* __restrict__ gn_w,
           const float* __restrict__ gn_b, float* __restrict__ sb)
{
    __shared__ float r1[256], r2[256];
    __shared__ float mean_s, rs_s;
    const int b = blockIdx.x, tid = threadIdx.x;
    r1[tid] = partials[2 * (b * 256 + tid)];
    r2[tid] = partials[2 * (b * 256 + tid) + 1];
    __syncthreads();
    #pragma unroll
    for (int st = 128; st > 0; st >>= 1) {
        if (tid < st) { r1[tid] += r1[tid + st]; r2[tid] += r2[tid + st]; }
        __syncthreads();
    }
    if (tid == 0) {
        const float n = (float)Cv * (float)Lv;
        const float mean = r1[0] / n;
        const float var  = r2[0] / n - mean * mean;
        mean_s = mean;
        rs_s   = rsqrtf(var + 1e-5f);
    }
    __syncthreads();
    if (tid < Cv) {
        const float sc = gn_w[tid] * rs_s;
        sb[b * Cv + tid]           = sc;
        sb[Bv * Cv + b * Cv + tid] = fmaf(-mean_s, sc, gn_b[tid]);
    }
}

// ---------------------------------------------------------------------------
// Pass 3: in-place GroupNorm affine on d_out (float4 vectorized).
// ---------------------------------------------------------------------------
__global__ __launch_bounds__(256)
void pass3(float* __restrict__ out, const float* __restrict__ sb)
{
    const int total4 = (Bv * Cv * Lv) / 4;   // 8388608
    for (int i = blockIdx.x * blockDim.x + threadIdx.x; i < total4;
         i += gridDim.x * blockDim.x) {
        const int row = i >> 14;            // / (L/4): row = b*64 + c
        const float sc = sb[row];
        const float bi = sb[Bv * Cv + row];
        float4 v = reinterpret_cast<float4*>(out)[i];
        v.x = fmaf(v.x, sc, bi);
        v.y = fmaf(v.y, sc, bi);
        v.z = fmaf(v.z, sc, bi);
        v.w = fmaf(v.w, sc, bi);
        reinterpret_cast<float4*>(out)[i] = v;
    }
}

extern "C" void kernel_launch(void* const* d_in, const int* in_sizes, int n_in,
                              void* d_out, int out_size, void* d_ws, size_t ws_size,
                              hipStream_t stream)
{
    const float* x      = (const float*)d_in[0];
    const float* inj0   = (const float*)d_in[1];
    const float* inj1   = (const float*)d_in[2];
    const float* resid  = (const float*)d_in[3];
    const float* gate_w = (const float*)d_in[4];
    const float* gate_b = (const float*)d_in[5];
    const float* fuse_w = (const float*)d_in[6];
    const float* fuse_b = (const float*)d_in[7];
    const float* gn_w   = (const float*)d_in[8];
    const float* gn_b   = (const float*)d_in[9];

    float* out      = (float*)d_out;
    float* ws       = (float*)d_ws;
    float* partials = ws;                 // 2 * 2048 floats = 16 KiB
    float* sb       = ws + 2 * GRID1;     // 2 * 512 floats  =  4 KiB

    hipLaunchKernelGGL(pass1, dim3(GRID1), dim3(TPB), 0, stream,
                       x, inj0, inj1, resid, gate_w, gate_b, fuse_w, fuse_b,
                       out, partials);
    hipLaunchKernelGGL(pass2, dim3(Bv), dim3(256), 0, stream,
                       partials, gn_w, gn_b, sb);
    hipLaunchKernelGGL(pass3, dim3(2048), dim3(256), 0, stream, out, sb);
}

// Round 2
// 284.773 us; speedup vs baseline: 1.9847x; 1.9847x over previous
//
#include <hip/hip_runtime.h>

#define Bv 8
#define Cv 64
#define Lv 65536
#define TPB 256
#define LOC_PER_BLK 256               // 64 quads * 4 locations
#define BLKS_PER_B (Lv / LOC_PER_BLK) // 256
#define GRID1 (Bv * BLKS_PER_B)       // 2048
#define L4 (Lv / 4)                   // 16384 float4s per channel row

__device__ __forceinline__ void fma_bcast(float w, const float4& v, float4& P) {
    P.x = fmaf(w, v.x, P.x);
    P.y = fmaf(w, v.y, P.y);
    P.z = fmaf(w, v.z, P.z);
    P.w = fmaf(w, v.w, P.w);
}

__device__ __forceinline__ void quad_reduce(float4& P) {
    P.x += __shfl_xor(P.x, 1); P.y += __shfl_xor(P.y, 1);
    P.z += __shfl_xor(P.z, 1); P.w += __shfl_xor(P.w, 1);
    P.x += __shfl_xor(P.x, 2); P.y += __shfl_xor(P.y, 2);
    P.z += __shfl_xor(P.z, 2); P.w += __shfl_xor(P.w, 2);
}

// ---------------------------------------------------------------------------
// Pass 1: quad-cluster fused gate + fuse conv + residual + ReLU.
// Cluster of 4 lanes owns 4 consecutive locations; lane owns 16 channels.
// All global traffic is float4. Weights in LDS (broadcast, 2-way = free).
// ---------------------------------------------------------------------------
__global__ __launch_bounds__(TPB, 3)
void pass1(const float* __restrict__ x, const float* __restrict__ inj0,
           const float* __restrict__ inj1, const float* __restrict__ resid,
           const float* __restrict__ gate_w, const float* __restrict__ gate_b,
           const float* __restrict__ fuse_w, const float* __restrict__ fuse_b,
           float* __restrict__ out, float* __restrict__ partials)
{
    __shared__ float gw[Cv * Cv];   // [o][c] row-major (as input)
    __shared__ float fwT[Cv * Cv];  // [o][c] = fuse_w[c][o]
    __shared__ float gb2[Cv], fb[Cv];
    __shared__ float r1[TPB], r2[TPB];

    const int tid = threadIdx.x;
    for (int i = tid; i < Cv * Cv; i += TPB) {
        gw[i]  = gate_w[i];
        fwT[i] = fuse_w[((i & 63) << 6) | (i >> 6)];
    }
    if (tid < Cv) { gb2[tid] = 2.0f * gate_b[tid]; fb[tid] = fuse_b[tid]; }
    __syncthreads();

    const int g  = tid & 3;    // channel-group within cluster (16 ch each)
    const int q  = tid >> 2;   // quad id within block (0..63)
    const int c0 = g << 4;     // first owned channel

    const int b    = blockIdx.x / BLKS_PER_B;
    const int lb   = blockIdx.x % BLKS_PER_B;
    // float4 index at (b, channel 0, quad start location)
    const int b4 = ((b * Cv * Lv) >> 2) + ((lb * LOC_PER_BLK) >> 2) + q;

    const float4* x4  = reinterpret_cast<const float4*>(x);
    const float4* i04 = reinterpret_cast<const float4*>(inj0);
    const float4* i14 = reinterpret_cast<const float4*>(inj1);
    const float4* rs4 = reinterpret_cast<const float4*>(resid);
    float4*       o4  = reinterpret_cast<float4*>(out);

    float4 s[16], t[16];
    #pragma unroll
    for (int j = 0; j < 16; ++j) {
        const int i4 = b4 + (c0 + j) * L4;
        const float4 a  = i04[i4];
        const float4 bb = i14[i4];
        const float4 xx = x4[i4];
        s[j].x = a.x + bb.x + 2.0f * xx.x;
        s[j].y = a.y + bb.y + 2.0f * xx.y;
        s[j].z = a.z + bb.z + 2.0f * xx.z;
        s[j].w = a.w + bb.w + 2.0f * xx.w;
        t[j] = make_float4(0.f, 0.f, 0.f, 0.f);
    }

    #pragma unroll 2
    for (int o = 0; o < Cv; ++o) {
        // gate partial dot over own 16 channels, 4 locations at once
        const float4* gr = reinterpret_cast<const float4*>(&gw[(o << 6) + c0]);
        float4 P = make_float4(0.f, 0.f, 0.f, 0.f);
        #pragma unroll
        for (int jq = 0; jq < 4; ++jq) {
            const float4 w = gr[jq];
            fma_bcast(w.x, s[4 * jq + 0], P);
            fma_bcast(w.y, s[4 * jq + 1], P);
            fma_bcast(w.z, s[4 * jq + 2], P);
            fma_bcast(w.w, s[4 * jq + 3], P);
        }
        quad_reduce(P);                       // full 64-ch dot on all 4 lanes
        const float gb = gb2[o];

        const float4 xq = x4[b4 + o * L4];    // quad's x at channel o (L1/L2)
        float4 acc;
        acc.x = xq.x * (P.x + gb);
        acc.y = xq.y * (P.y + gb);
        acc.z = xq.z * (P.z + gb);
        acc.w = xq.w * (P.w + gb);

        // scatter into own 16 output channels
        const float4* fr = reinterpret_cast<const float4*>(&fwT[(o << 6) + c0]);
        #pragma unroll
        for (int jq = 0; jq < 4; ++jq) {
            const float4 w = fr[jq];
            fma_bcast(w.x, acc, t[4 * jq + 0]);
            fma_bcast(w.y, acc, t[4 * jq + 1]);
            fma_bcast(w.z, acc, t[4 * jq + 2]);
            fma_bcast(w.w, acc, t[4 * jq + 3]);
        }
    }

    // Epilogue: bias + residual + ReLU, store pre-GN output, local stats.
    float lsum = 0.0f, lsq = 0.0f;
    #pragma unroll
    for (int j = 0; j < 16; ++j) {
        const int i4 = b4 + (c0 + j) * L4;
        const float4 r  = rs4[i4];
        const float fbias = fb[c0 + j];
        float4 v;
        v.x = fmaxf(t[j].x + fbias + r.x, 0.0f);
        v.y = fmaxf(t[j].y + fbias + r.y, 0.0f);
        v.z = fmaxf(t[j].z + fbias + r.z, 0.0f);
        v.w = fmaxf(t[j].w + fbias + r.w, 0.0f);
        o4[i4] = v;
        lsum += (v.x + v.y) + (v.z + v.w);
        lsq = fmaf(v.x, v.x, lsq);
        lsq = fmaf(v.y, v.y, lsq);
        lsq = fmaf(v.z, v.z, lsq);
        lsq = fmaf(v.w, v.w, lsq);
    }

    r1[tid] = lsum; r2[tid] = lsq;
    __syncthreads();
    #pragma unroll
    for (int st = TPB / 2; st > 0; st >>= 1) {
        if (tid < st) { r1[tid] += r1[tid + st]; r2[tid] += r2[tid + st]; }
        __syncthreads();
    }
    if (tid == 0) {
        partials[2 * blockIdx.x]     = r1[0];
        partials[2 * blockIdx.x + 1] = r2[0];
    }
}

// ---------------------------------------------------------------------------
// Pass 2: reduce 256 partials per batch -> per-(b,c) scale/bias.
// ---------------------------------------------------------------------------
__global__ __launch_bounds__(256)
void pass2(const float* __restrict__ partials, const float* __restrict__ gn_w,
           const float* __restrict__ gn_b, float* __restrict__ sb)
{
    __shared__ float r1[256], r2[256];
    __shared__ float mean_s, rs_s;
    const int b = blockIdx.x, tid = threadIdx.x;
    r1[tid] = partials[2 * (b * 256 + tid)];
    r2[tid] = partials[2 * (b * 256 + tid) + 1];
    __syncthreads();
    #pragma unroll
    for (int st = 128; st > 0; st >>= 1) {
        if (tid < st) { r1[tid] += r1[tid + st]; r2[tid] += r2[tid + st]; }
        __syncthreads();
    }
    if (tid == 0) {
        const float n = (float)Cv * (float)Lv;
        const float mean = r1[0] / n;
        const float var  = r2[0] / n - mean * mean;
        mean_s = mean;
        rs_s   = rsqrtf(var + 1e-5f);
    }
    __syncthreads();
    if (tid < Cv) {
        const float sc = gn_w[tid] * rs_s;
        sb[b * Cv + tid]           = sc;
        sb[Bv * Cv + b * Cv + tid] = fmaf(-mean_s, sc, gn_b[tid]);
    }
}

// ---------------------------------------------------------------------------
// Pass 3: in-place GroupNorm affine on d_out (float4 vectorized).
// ---------------------------------------------------------------------------
__global__ __launch_bounds__(256)
void pass3(float* __restrict__ out, const float* __restrict__ sb)
{
    const int total4 = (Bv * Cv * Lv) / 4;   // 8388608
    for (int i = blockIdx.x * blockDim.x + threadIdx.x; i < total4;
         i += gridDim.x * blockDim.x) {
        const int row = i >> 14;            // / (L/4): row = b*64 + c
        const float sc = sb[row];
        const float bi = sb[Bv * Cv + row];
        float4 v = reinterpret_cast<float4*>(out)[i];
        v.x = fmaf(v.x, sc, bi);
        v.y = fmaf(v.y, sc, bi);
        v.z = fmaf(v.z, sc, bi);
        v.w = fmaf(v.w, sc, bi);
        reinterpret_cast<float4*>(out)[i] = v;
    }
}

extern "C" void kernel_launch(void* const* d_in, const int* in_sizes, int n_in,
                              void* d_out, int out_size, void* d_ws, size_t ws_size,
                              hipStream_t stream)
{
    const float* x      = (const float*)d_in[0];
    const float* inj0   = (const float*)d_in[1];
    const float* inj1   = (const float*)d_in[2];
    const float* resid  = (const float*)d_in[3];
    const float* gate_w = (const float*)d_in[4];
    const float* gate_b = (const float*)d_in[5];
    const float* fuse_w = (const float*)d_in[6];
    const float* fuse_b = (const float*)d_in[7];
    const float* gn_w   = (const float*)d_in[8];
    const float* gn_b   = (const float*)d_in[9];

    float* out      = (float*)d_out;
    float* ws       = (float*)d_ws;
    float* partials = ws;                 // 2 * 2048 floats = 16 KiB
    float* sb       = ws + 2 * GRID1;     // 2 * 512 floats  =  4 KiB

    hipLaunchKernelGGL(pass1, dim3(GRID1), dim3(TPB), 0, stream,
                       x, inj0, inj1, resid, gate_w, gate_b, fuse_w, fuse_b,
                       out, partials);
    hipLaunchKernelGGL(pass2, dim3(Bv), dim3(256), 0, stream,
                       partials, gn_w, gn_b, sb);
    hipLaunchKernelGGL(pass3, dim3(2048), dim3(256), 0, stream, out, sb);
}